// Round 4
// baseline (109.313 us; speedup 1.0000x reference)
//
#include <hip/hip_runtime.h>
#include <hip/hip_bf16.h>

#define BATCH 4
#define SEQ   4096
#define EMB   1024
#define HS    64

typedef __attribute__((ext_vector_type(4))) short  short4v;
typedef __attribute__((ext_vector_type(4))) float  float4v;
typedef __attribute__((ext_vector_type(8))) unsigned short ushort8v;

// Q pre-scale: 1/sqrt(64) * log2(e) so softmax can use exp2 directly.
#define QSCALE 0.1803368801111204f

static __device__ __forceinline__ unsigned short f2bf(float f){
  __hip_bfloat16 h = __float2bfloat16(f);
  return *reinterpret_cast<unsigned short*>(&h);
}

// D = A*B + C, 16x16x16 bf16 (K=16).
//  A: lane l holds A[l%16][4*(l/16)+j], j=0..3
//  B: lane l holds B[4*(l/16)+j][l%16]
//  C/D: lane l holds D[4*(l/16)+reg][l%16]
static __device__ __forceinline__ float4v mfma16(short4v a, short4v b, float4v c){
#if __has_builtin(__builtin_amdgcn_mfma_f32_16x16x16bf16_1k)
  return __builtin_amdgcn_mfma_f32_16x16x16bf16_1k(a, b, c, 0, 0, 0);
#else
  float4v d;
  asm("v_mfma_f32_16x16x16_bf16 %0, %1, %2, %3" : "=v"(d) : "v"(a), "v"(b), "v"(c));
  return d;
#endif
}

// ---------------- W pack: fp32 [1024][64] x3 -> bf16 fragment-major ----------------
// Wpack[kstep][ks][nt][lane][j]  (16*4*12*64*4 ushorts = 384 KB)
//   holds B[k][n], k = kstep*64 + ks*16 + (lane>>4)*4 + j, n = nt*16 + (lane&15)
//   nt 0..3 -> Q (scaled by QSCALE), 4..7 -> K, 8..11 -> V
__global__ __launch_bounds__(256) void pack_kernel(
    const float* __restrict__ Wq, const float* __restrict__ Wk, const float* __restrict__ Wv,
    unsigned short* __restrict__ Wpack){
  const int flat = blockIdx.x * 256 + threadIdx.x;       // 0..49151
  const int lane = flat & 63;
  const int f    = flat >> 6;
  const int nt   = f % 12;
  const int ks   = (f / 12) & 3;
  const int kstep= f / 48;
  const int k0   = kstep * 64 + ks * 16 + (lane >> 4) * 4;
  const int h    = (nt & 3) * 16 + (lane & 15);
  const int mat  = nt >> 2;
  const float* W = (mat == 0) ? Wq : (mat == 1) ? Wk : Wv;
  const float scale = (mat == 0) ? QSCALE : 1.0f;
  short4v pk;
  #pragma unroll
  for (int j = 0; j < 4; ++j) pk[j] = (short)f2bf(W[(size_t)(k0 + j) * HS + h] * scale);
  *reinterpret_cast<short4v*>(Wpack + (size_t)flat * 4) = pk;
}

// ---------------- projection GEMM: LDS-free MFMA, column-split for occupancy ----------------
// Grid 1024 blocks x 4 waves. Block owns 16 rows; wave w owns output tiles nt = 3w..3w+2.
__global__ __launch_bounds__(256) void proj_mfma(
    const float* __restrict__ x, const unsigned short* __restrict__ Wpack,
    unsigned short* __restrict__ Qb, unsigned short* __restrict__ Kb,
    unsigned short* __restrict__ Vt){
  const int tid  = threadIdx.x;
  const int lane = tid & 63;
  const int w    = tid >> 6;
  const int ln   = lane & 15;
  const int lg   = lane >> 4;
  const int grow0 = blockIdx.x * 16;
  const int nt0 = w * 3;

  float4v acc0 = (float4v){0.f,0.f,0.f,0.f};
  float4v acc1 = (float4v){0.f,0.f,0.f,0.f};
  float4v acc2 = (float4v){0.f,0.f,0.f,0.f};

  const float* xrow = x + (size_t)(grow0 + ln) * EMB + lg * 4;
  const unsigned short* wp = Wpack + (size_t)nt0 * 256 + lane * 4;

  #pragma unroll 4
  for (int kstep = 0; kstep < 16; ++kstep){
    // A fragments: per-lane 16B fp32 load + bf16 convert
    short4v af[4];
    #pragma unroll
    for (int ks = 0; ks < 4; ++ks){
      float4 xv = *reinterpret_cast<const float4*>(xrow + kstep * 64 + ks * 16);
      short4v a;
      a[0] = (short)f2bf(xv.x); a[1] = (short)f2bf(xv.y);
      a[2] = (short)f2bf(xv.z); a[3] = (short)f2bf(xv.w);
      af[ks] = a;
    }
    // B fragments from L1/L2-resident Wpack (lane-linear 8B loads, 3 contiguous tiles)
    #pragma unroll
    for (int ks = 0; ks < 4; ++ks){
      const unsigned short* wk = wp + (size_t)(kstep * 4 + ks) * 12 * 256;
      acc0 = mfma16(af[ks], *reinterpret_cast<const short4v*>(wk),       acc0);
      acc1 = mfma16(af[ks], *reinterpret_cast<const short4v*>(wk + 256), acc1);
      acc2 = mfma16(af[ks], *reinterpret_cast<const short4v*>(wk + 512), acc2);
    }
  }

  // ---- epilogue: D[4*lg+r][ln] per tile; wave's 3 tiles span Q/K/V regions ----
  const int row0 = grow0 + 4 * lg;
  const float4v accs[3] = {acc0, acc1, acc2};
  #pragma unroll
  for (int j = 0; j < 3; ++j){
    const int nt  = nt0 + j;
    const int mat = nt >> 2;
    const int loc = nt & 3;
    if (mat == 0){
      #pragma unroll
      for (int r = 0; r < 4; ++r)
        Qb[(size_t)(row0 + r) * HS + loc * 16 + ln] = f2bf(accs[j][r]);
    } else if (mat == 1){
      #pragma unroll
      for (int r = 0; r < 4; ++r)
        Kb[(size_t)(row0 + r) * HS + loc * 16 + ln] = f2bf(accs[j][r]);
    } else {
      short4v pk;
      #pragma unroll
      for (int r = 0; r < 4; ++r) pk[r] = (short)f2bf(accs[j][r]);
      *reinterpret_cast<short4v*>(Vt + (size_t)(loc * 16 + ln) * (BATCH * SEQ) + row0) = pk;
    }
  }
}

// ---------------- flash attention partials, causal, kv-split ----------------
template<int CHUNK>
__global__ __launch_bounds__(256) void attn_partial(
    const unsigned short* __restrict__ Qb, const unsigned short* __restrict__ Kb,
    const unsigned short* __restrict__ Vt,
    float* __restrict__ Opart, float* __restrict__ Mpart, float* __restrict__ Lpart){
  constexpr int GS  = CHUNK / 64;
  constexpr int NG  = SEQ / CHUNK;
  constexpr int PCB = GS * NG * (NG + 1) / 2;
  constexpr int LDP = 72;

  __shared__ unsigned short Ks[64 * LDP];
  __shared__ unsigned short Vs[64 * LDP];

  const int b = blockIdx.x / PCB;
  const int g = blockIdx.x % PCB;
  int a = 0, accb = 0;
  while (g >= accb + GS * (a + 1)) { accb += GS * (a + 1); ++a; }
  const int rem = g - accb;
  const int qj  = a * GS + rem / (a + 1);
  const int c   = rem % (a + 1);

  const int tid  = threadIdx.x;
  const int lane = tid & 63;
  const int w    = tid >> 6;
  const int ln   = lane & 15;
  const int lg   = lane >> 4;

  const size_t bbase = (size_t)b * SEQ * HS;
  const int qbase  = qj * 64 + w * 16;
  const int cstart = c * CHUNK;
  const int kend   = min(cstart + CHUNK, qj * 64 + 64);
  const int nt     = (kend - cstart) >> 6;

  short4v qf[4];
  #pragma unroll
  for (int ds = 0; ds < 4; ++ds)
    qf[ds] = *reinterpret_cast<const short4v*>(Qb + bbase + (size_t)(qbase + ln) * HS + ds * 16 + lg * 4);

  float m = -1e30f, lsum = 0.f;
  float4v oacc[4];
  #pragma unroll
  for (int dt = 0; dt < 4; ++dt) oacc[dt] = (float4v){0.f, 0.f, 0.f, 0.f};

  const int srow = tid >> 2;
  const int sseg = tid & 3;
  const unsigned short* Kg = Kb + bbase + (size_t)(cstart + srow) * HS + sseg * 16;
  const unsigned short* Vg = Vt + (size_t)srow * (BATCH * SEQ) + b * SEQ + cstart + sseg * 16;
  ushort8v kr0, kr1, vr0, vr1;
  kr0 = reinterpret_cast<const ushort8v*>(Kg)[0];
  kr1 = reinterpret_cast<const ushort8v*>(Kg)[1];
  vr0 = reinterpret_cast<const ushort8v*>(Vg)[0];
  vr1 = reinterpret_cast<const ushort8v*>(Vg)[1];

  for (int t = 0; t < nt; ++t){
    *reinterpret_cast<ushort8v*>(&Ks[srow * LDP + sseg * 16])     = kr0;
    *reinterpret_cast<ushort8v*>(&Ks[srow * LDP + sseg * 16 + 8]) = kr1;
    *reinterpret_cast<ushort8v*>(&Vs[srow * LDP + sseg * 16])     = vr0;
    *reinterpret_cast<ushort8v*>(&Vs[srow * LDP + sseg * 16 + 8]) = vr1;
    __syncthreads();
    if (t + 1 < nt){
      const unsigned short* Kn = Kg + (size_t)(t + 1) * 64 * HS;
      const unsigned short* Vn = Vg + (t + 1) * 64;
      kr0 = reinterpret_cast<const ushort8v*>(Kn)[0];
      kr1 = reinterpret_cast<const ushort8v*>(Kn)[1];
      vr0 = reinterpret_cast<const ushort8v*>(Vn)[0];
      vr1 = reinterpret_cast<const ushort8v*>(Vn)[1];
    }

    const int k0 = cstart + t * 64;
    if (k0 <= qbase + 15){
      float4v st[4];
      #pragma unroll
      for (int kt = 0; kt < 4; ++kt){
        float4v accv = (float4v){0.f, 0.f, 0.f, 0.f};
        #pragma unroll
        for (int ds = 0; ds < 4; ++ds){
          short4v av = *reinterpret_cast<const short4v*>(&Ks[(kt * 16 + ln) * LDP + ds * 16 + lg * 4]);
          accv = mfma16(av, qf[ds], accv);
        }
        st[kt] = accv;
      }
      const int gq = qbase + ln;
      #pragma unroll
      for (int kt = 0; kt < 4; ++kt){
        if (k0 + kt * 16 + 15 > qbase){
          #pragma unroll
          for (int r = 0; r < 4; ++r){
            const int gk = k0 + kt * 16 + lg * 4 + r;
            if (gk > gq) st[kt][r] = -1e30f;
          }
        }
      }
      float tmax = -1e30f;
      #pragma unroll
      for (int kt = 0; kt < 4; ++kt)
        #pragma unroll
        for (int r = 0; r < 4; ++r) tmax = fmaxf(tmax, st[kt][r]);
      tmax = fmaxf(tmax, __shfl_xor(tmax, 16, 64));
      tmax = fmaxf(tmax, __shfl_xor(tmax, 32, 64));
      const float mnew = fmaxf(m, tmax);
      const float corr = exp2f(m - mnew);
      float psum = 0.f;
      short4v pb[4];
      #pragma unroll
      for (int kt = 0; kt < 4; ++kt){
        #pragma unroll
        for (int r = 0; r < 4; ++r){
          const float p = exp2f(st[kt][r] - mnew);
          psum += p;
          pb[kt][r] = (short)f2bf(p);
        }
      }
      psum += __shfl_xor(psum, 16, 64);
      psum += __shfl_xor(psum, 32, 64);
      lsum = lsum * corr + psum;
      m = mnew;
      #pragma unroll
      for (int dt = 0; dt < 4; ++dt){
        oacc[dt][0] *= corr; oacc[dt][1] *= corr; oacc[dt][2] *= corr; oacc[dt][3] *= corr;
      }
      #pragma unroll
      for (int dt = 0; dt < 4; ++dt){
        #pragma unroll
        for (int kt = 0; kt < 4; ++kt){
          short4v av = *reinterpret_cast<const short4v*>(&Vs[(dt * 16 + ln) * LDP + kt * 16 + lg * 4]);
          oacc[dt] = mfma16(av, pb[kt], oacc[dt]);
        }
      }
    }
    __syncthreads();
  }

  const int p = b * PCB + g;
  const int ql = w * 16 + ln;
  float* Op = Opart + ((size_t)p * 64 + ql) * 64;
  #pragma unroll
  for (int dt = 0; dt < 4; ++dt)
    *reinterpret_cast<float4v*>(Op + dt * 16 + lg * 4) = oacc[dt];
  if (lg == 0){
    Mpart[p * 64 + ql] = m;
    Lpart[p * 64 + ql] = lsum;
  }
}

// ---------------- combine partials ----------------
template<int CHUNK>
__global__ __launch_bounds__(256) void combine_kernel(
    const float* __restrict__ Opart, const float* __restrict__ Mpart,
    const float* __restrict__ Lpart, float* __restrict__ out){
  constexpr int GS  = CHUNK / 64;
  constexpr int NG  = SEQ / CHUNK;
  constexpr int PCB = GS * NG * (NG + 1) / 2;
  const int gid = blockIdx.x * 4 + (threadIdx.x >> 6);
  const int d   = threadIdx.x & 63;
  const int b   = gid >> 12;
  const int q   = gid & (SEQ - 1);
  const int qj  = q >> 6;
  const int a   = qj / GS;
  const int nch = a + 1;
  const int p0  = b * PCB + GS * a * (a + 1) / 2 + (qj - a * GS) * (a + 1);
  const int ql  = q & 63;

  float M = -1e30f;
  for (int cc = 0; cc < nch; ++cc) M = fmaxf(M, Mpart[(p0 + cc) * 64 + ql]);
  float L = 0.f, O = 0.f;
  for (int cc = 0; cc < nch; ++cc){
    const float s = exp2f(Mpart[(p0 + cc) * 64 + ql] - M);
    L += s * Lpart[(p0 + cc) * 64 + ql];
    O += s * Opart[((size_t)(p0 + cc) * 64 + ql) * 64 + d];
  }
  out[(size_t)gid * 64 + d] = O / L;
}

extern "C" void kernel_launch(void* const* d_in, const int* in_sizes, int n_in,
                              void* d_out, int out_size, void* d_ws, size_t ws_size,
                              hipStream_t stream){
  const float* x  = (const float*)d_in[0];
  const float* Wq = (const float*)d_in[1];
  const float* Wk = (const float*)d_in[2];
  const float* Wv = (const float*)d_in[3];

  const size_t nqkv = (size_t)BATCH * SEQ * HS;
  unsigned short* Qb = (unsigned short*)d_ws;
  unsigned short* Kb = Qb + nqkv;
  unsigned short* Vt = Kb + nqkv;                     // [HS][BATCH*SEQ]
  unsigned short* Wpack = Vt + nqkv;                  // 196608 ushorts = 384 KB
  float* scratch = (float*)(Wpack + (size_t)16 * 4 * 12 * 64 * 4);

  pack_kernel<<<192, 256, 0, stream>>>(Wq, Wk, Wv, Wpack);
  proj_mfma<<<(BATCH * SEQ) / 16, 256, 0, stream>>>(x, Wpack, Qb, Kb, Vt);

  constexpr int PCB1 = (1024/64) * (SEQ/1024) * ((SEQ/1024) + 1) / 2;   // 160
  constexpr int PCB4 = (4096/64) * (SEQ/4096) * ((SEQ/4096) + 1) / 2;   // 64
  const size_t base_bytes = (3 * nqkv + (size_t)196608) * sizeof(unsigned short);
  const size_t part1 = (size_t)BATCH * PCB1 * 64 * (64 + 2) * sizeof(float);

  if (ws_size >= base_bytes + part1){
    float* Opart = scratch;
    float* Mpart = Opart + (size_t)BATCH * PCB1 * 64 * 64;
    float* Lpart = Mpart + (size_t)BATCH * PCB1 * 64;
    attn_partial<1024><<<BATCH * PCB1, 256, 0, stream>>>(Qb, Kb, Vt, Opart, Mpart, Lpart);
    combine_kernel<1024><<<BATCH * SEQ / 4, 256, 0, stream>>>(Opart, Mpart, Lpart, (float*)d_out);
  } else {
    float* Opart = scratch;
    float* Mpart = Opart + (size_t)BATCH * PCB4 * 64 * 64;
    float* Lpart = Mpart + (size_t)BATCH * PCB4 * 64;
    attn_partial<4096><<<BATCH * PCB4, 256, 0, stream>>>(Qb, Kb, Vt, Opart, Mpart, Lpart);
    combine_kernel<4096><<<BATCH * SEQ / 4, 256, 0, stream>>>(Opart, Mpart, Lpart, (float*)d_out);
  }
}

// Round 5
// 89.667 us; speedup vs baseline: 1.2191x; 1.2191x over previous
//
#include <hip/hip_runtime.h>
#include <hip/hip_bf16.h>

#define BATCH 4
#define SEQ   4096
#define EMB   1024
#define HS    64

typedef __attribute__((ext_vector_type(4))) short  short4v;
typedef __attribute__((ext_vector_type(4))) float  float4v;
typedef __attribute__((ext_vector_type(8))) unsigned short ushort8v;

// Q pre-scale: 1/sqrt(64) * log2(e) so softmax can use exp2 directly.
#define QSCALE 0.1803368801111204f

static __device__ __forceinline__ unsigned short f2bf(float f){
  __hip_bfloat16 h = __float2bfloat16(f);
  return *reinterpret_cast<unsigned short*>(&h);
}

// D = A*B + C, 16x16x16 bf16 (K=16).
//  A: lane l holds A[l%16][4*(l/16)+j], j=0..3
//  B: lane l holds B[4*(l/16)+j][l%16]
//  C/D: lane l holds D[4*(l/16)+reg][l%16]
static __device__ __forceinline__ float4v mfma16(short4v a, short4v b, float4v c){
#if __has_builtin(__builtin_amdgcn_mfma_f32_16x16x16bf16_1k)
  return __builtin_amdgcn_mfma_f32_16x16x16bf16_1k(a, b, c, 0, 0, 0);
#else
  float4v d;
  asm("v_mfma_f32_16x16x16_bf16 %0, %1, %2, %3" : "=v"(d) : "v"(a), "v"(b), "v"(c));
  return d;
#endif
}

// ---------------- W pack: fp32 [1024][64] x3 -> bf16 fragment-major ----------------
// Wpack[kstep][ks][nt][lane][j]  (16*4*12*64*4 ushorts = 384 KB)
//   holds B[k][n], k = kstep*64 + ks*16 + (lane>>4)*4 + j, n = nt*16 + (lane&15)
//   nt 0..3 -> Q (scaled by QSCALE), 4..7 -> K, 8..11 -> V
__global__ __launch_bounds__(256) void pack_kernel(
    const float* __restrict__ Wq, const float* __restrict__ Wk, const float* __restrict__ Wv,
    unsigned short* __restrict__ Wpack){
  const int flat = blockIdx.x * 256 + threadIdx.x;       // 0..49151
  const int lane = flat & 63;
  const int f    = flat >> 6;
  const int nt   = f % 12;
  const int ks   = (f / 12) & 3;
  const int kstep= f / 48;
  const int k0   = kstep * 64 + ks * 16 + (lane >> 4) * 4;
  const int h    = (nt & 3) * 16 + (lane & 15);
  const int mat  = nt >> 2;
  const float* W = (mat == 0) ? Wq : (mat == 1) ? Wk : Wv;
  const float scale = (mat == 0) ? QSCALE : 1.0f;
  short4v pk;
  #pragma unroll
  for (int j = 0; j < 4; ++j) pk[j] = (short)f2bf(W[(size_t)(k0 + j) * HS + h] * scale);
  *reinterpret_cast<short4v*>(Wpack + (size_t)flat * 4) = pk;
}

// ---------------- projection GEMM: K-split MFMA ----------------
// Block: 512 threads = 8 waves = (kq 0..3 K-quarters) x (wr 0..1 row-groups of 16).
// Block owns 32 rows x 192 cols; fp32 partials reduced through LDS.
// Grid: 512 blocks (2/CU) -> 16 waves/CU = 4/SIMD.
#define LP 198   // padded LDS row stride (floats); 198%32=6 -> max 2-way bank aliasing
__global__ __launch_bounds__(512, 4) void proj_mfma(
    const float* __restrict__ x, const unsigned short* __restrict__ Wpack,
    unsigned short* __restrict__ Qb, unsigned short* __restrict__ Kb,
    unsigned short* __restrict__ Vt){
  __shared__ float Red[32 * LP];                  // 25.3 KB
  const int tid  = threadIdx.x;
  const int lane = tid & 63;
  const int w    = tid >> 6;                      // 0..7
  const int kq   = w >> 1;                        // K-quarter 0..3
  const int wr   = w & 1;                         // row-group 0..1
  const int ln   = lane & 15;
  const int lg   = lane >> 4;
  const int grow0 = blockIdx.x * 32;
  const int row16 = grow0 + wr * 16;

  float4v acc[12];
  #pragma unroll
  for (int nt = 0; nt < 12; ++nt) acc[nt] = (float4v){0.f, 0.f, 0.f, 0.f};

  const float* xrow = x + (size_t)(row16 + ln) * EMB + kq * 256 + lg * 4;
  const unsigned short* wp = Wpack + lane * 4;

  // prefetch first kstep's A values
  float4 xv[4];
  #pragma unroll
  for (int ks = 0; ks < 4; ++ks)
    xv[ks] = *reinterpret_cast<const float4*>(xrow + ks * 16);

  #pragma unroll
  for (int k4 = 0; k4 < 4; ++k4){
    // convert current A, then issue next prefetch (overlaps MFMAs below)
    short4v af[4];
    #pragma unroll
    for (int ks = 0; ks < 4; ++ks){
      short4v a;
      a[0] = (short)f2bf(xv[ks].x); a[1] = (short)f2bf(xv[ks].y);
      a[2] = (short)f2bf(xv[ks].z); a[3] = (short)f2bf(xv[ks].w);
      af[ks] = a;
    }
    if (k4 < 3){
      #pragma unroll
      for (int ks = 0; ks < 4; ++ks)
        xv[ks] = *reinterpret_cast<const float4*>(xrow + (k4 + 1) * 64 + ks * 16);
    }
    const int kstep = kq * 4 + k4;
    #pragma unroll
    for (int ks = 0; ks < 4; ++ks){
      const unsigned short* wk = wp + (size_t)((kstep * 4 + ks) * 12) * 256;
      #pragma unroll
      for (int nt = 0; nt < 12; ++nt)   // 12 independent MFMA chains
        acc[nt] = mfma16(af[ks], *reinterpret_cast<const short4v*>(wk + nt * 256), acc[nt]);
    }
  }

  // ---- LDS reduction over the 4 K-quarters (sequential accumulate) ----
  // lane holds D[4*lg+r][16*nt+ln] for rows row16..row16+15
  if (kq == 0){
    #pragma unroll
    for (int nt = 0; nt < 12; ++nt)
      #pragma unroll
      for (int r = 0; r < 4; ++r)
        Red[(wr * 16 + 4 * lg + r) * LP + nt * 16 + ln] = acc[nt][r];
  }
  __syncthreads();
  #pragma unroll
  for (int rd = 1; rd < 4; ++rd){
    if (kq == rd){
      #pragma unroll
      for (int nt = 0; nt < 12; ++nt)
        #pragma unroll
        for (int r = 0; r < 4; ++r)
          Red[(wr * 16 + 4 * lg + r) * LP + nt * 16 + ln] += acc[nt][r];
    }
    __syncthreads();
  }

  // ---- epilogue: cols 0..63 -> Q, 64..127 -> K (row-major), 128..191 -> V (transposed) ----
  {
    const int row = tid >> 4;                     // 0..31
    const int cg  = tid & 15;                     // 0..15
    ushort8v pk;
    #pragma unroll
    for (int i = 0; i < 8; ++i) pk[i] = f2bf(Red[row * LP + cg * 8 + i]);
    unsigned short* dst = (cg < 8) ? (Qb + (size_t)(grow0 + row) * HS + cg * 8)
                                   : (Kb + (size_t)(grow0 + row) * HS + (cg - 8) * 8);
    *reinterpret_cast<ushort8v*>(dst) = pk;
  }
  {
    const int vcol = tid >> 3;                    // 0..63
    const int rg   = tid & 7;                     // 0..7
    short4v pk;
    #pragma unroll
    for (int j = 0; j < 4; ++j) pk[j] = (short)f2bf(Red[(rg * 4 + j) * LP + 128 + vcol]);
    *reinterpret_cast<short4v*>(Vt + (size_t)vcol * (BATCH * SEQ) + grow0 + rg * 4) = pk;
  }
}

// ---------------- flash attention partials, causal, kv-split ----------------
template<int CHUNK>
__global__ __launch_bounds__(256) void attn_partial(
    const unsigned short* __restrict__ Qb, const unsigned short* __restrict__ Kb,
    const unsigned short* __restrict__ Vt,
    float* __restrict__ Opart, float* __restrict__ Mpart, float* __restrict__ Lpart){
  constexpr int GS  = CHUNK / 64;
  constexpr int NG  = SEQ / CHUNK;
  constexpr int PCB = GS * NG * (NG + 1) / 2;
  constexpr int LDP = 72;

  __shared__ unsigned short Ks[64 * LDP];
  __shared__ unsigned short Vs[64 * LDP];

  const int b = blockIdx.x / PCB;
  const int g = blockIdx.x % PCB;
  int a = 0, accb = 0;
  while (g >= accb + GS * (a + 1)) { accb += GS * (a + 1); ++a; }
  const int rem = g - accb;
  const int qj  = a * GS + rem / (a + 1);
  const int c   = rem % (a + 1);

  const int tid  = threadIdx.x;
  const int lane = tid & 63;
  const int w    = tid >> 6;
  const int ln   = lane & 15;
  const int lg   = lane >> 4;

  const size_t bbase = (size_t)b * SEQ * HS;
  const int qbase  = qj * 64 + w * 16;
  const int cstart = c * CHUNK;
  const int kend   = min(cstart + CHUNK, qj * 64 + 64);
  const int nt     = (kend - cstart) >> 6;

  short4v qf[4];
  #pragma unroll
  for (int ds = 0; ds < 4; ++ds)
    qf[ds] = *reinterpret_cast<const short4v*>(Qb + bbase + (size_t)(qbase + ln) * HS + ds * 16 + lg * 4);

  float m = -1e30f, lsum = 0.f;
  float4v oacc[4];
  #pragma unroll
  for (int dt = 0; dt < 4; ++dt) oacc[dt] = (float4v){0.f, 0.f, 0.f, 0.f};

  const int srow = tid >> 2;
  const int sseg = tid & 3;
  const unsigned short* Kg = Kb + bbase + (size_t)(cstart + srow) * HS + sseg * 16;
  const unsigned short* Vg = Vt + (size_t)srow * (BATCH * SEQ) + b * SEQ + cstart + sseg * 16;
  ushort8v kr0, kr1, vr0, vr1;
  kr0 = reinterpret_cast<const ushort8v*>(Kg)[0];
  kr1 = reinterpret_cast<const ushort8v*>(Kg)[1];
  vr0 = reinterpret_cast<const ushort8v*>(Vg)[0];
  vr1 = reinterpret_cast<const ushort8v*>(Vg)[1];

  for (int t = 0; t < nt; ++t){
    *reinterpret_cast<ushort8v*>(&Ks[srow * LDP + sseg * 16])     = kr0;
    *reinterpret_cast<ushort8v*>(&Ks[srow * LDP + sseg * 16 + 8]) = kr1;
    *reinterpret_cast<ushort8v*>(&Vs[srow * LDP + sseg * 16])     = vr0;
    *reinterpret_cast<ushort8v*>(&Vs[srow * LDP + sseg * 16 + 8]) = vr1;
    __syncthreads();
    if (t + 1 < nt){
      const unsigned short* Kn = Kg + (size_t)(t + 1) * 64 * HS;
      const unsigned short* Vn = Vg + (t + 1) * 64;
      kr0 = reinterpret_cast<const ushort8v*>(Kn)[0];
      kr1 = reinterpret_cast<const ushort8v*>(Kn)[1];
      vr0 = reinterpret_cast<const ushort8v*>(Vn)[0];
      vr1 = reinterpret_cast<const ushort8v*>(Vn)[1];
    }

    const int k0 = cstart + t * 64;
    if (k0 <= qbase + 15){
      float4v st[4];
      #pragma unroll
      for (int kt = 0; kt < 4; ++kt){
        float4v accv = (float4v){0.f, 0.f, 0.f, 0.f};
        #pragma unroll
        for (int ds = 0; ds < 4; ++ds){
          short4v av = *reinterpret_cast<const short4v*>(&Ks[(kt * 16 + ln) * LDP + ds * 16 + lg * 4]);
          accv = mfma16(av, qf[ds], accv);
        }
        st[kt] = accv;
      }
      const int gq = qbase + ln;
      #pragma unroll
      for (int kt = 0; kt < 4; ++kt){
        if (k0 + kt * 16 + 15 > qbase){
          #pragma unroll
          for (int r = 0; r < 4; ++r){
            const int gk = k0 + kt * 16 + lg * 4 + r;
            if (gk > gq) st[kt][r] = -1e30f;
          }
        }
      }
      float tmax = -1e30f;
      #pragma unroll
      for (int kt = 0; kt < 4; ++kt)
        #pragma unroll
        for (int r = 0; r < 4; ++r) tmax = fmaxf(tmax, st[kt][r]);
      tmax = fmaxf(tmax, __shfl_xor(tmax, 16, 64));
      tmax = fmaxf(tmax, __shfl_xor(tmax, 32, 64));
      const float mnew = fmaxf(m, tmax);
      const float corr = exp2f(m - mnew);
      float psum = 0.f;
      short4v pb[4];
      #pragma unroll
      for (int kt = 0; kt < 4; ++kt){
        #pragma unroll
        for (int r = 0; r < 4; ++r){
          const float p = exp2f(st[kt][r] - mnew);
          psum += p;
          pb[kt][r] = (short)f2bf(p);
        }
      }
      psum += __shfl_xor(psum, 16, 64);
      psum += __shfl_xor(psum, 32, 64);
      lsum = lsum * corr + psum;
      m = mnew;
      #pragma unroll
      for (int dt = 0; dt < 4; ++dt){
        oacc[dt][0] *= corr; oacc[dt][1] *= corr; oacc[dt][2] *= corr; oacc[dt][3] *= corr;
      }
      #pragma unroll
      for (int dt = 0; dt < 4; ++dt){
        #pragma unroll
        for (int kt = 0; kt < 4; ++kt){
          short4v av = *reinterpret_cast<const short4v*>(&Vs[(dt * 16 + ln) * LDP + kt * 16 + lg * 4]);
          oacc[dt] = mfma16(av, pb[kt], oacc[dt]);
        }
      }
    }
    __syncthreads();
  }

  const int p = b * PCB + g;
  const int ql = w * 16 + ln;
  float* Op = Opart + ((size_t)p * 64 + ql) * 64;
  #pragma unroll
  for (int dt = 0; dt < 4; ++dt)
    *reinterpret_cast<float4v*>(Op + dt * 16 + lg * 4) = oacc[dt];
  if (lg == 0){
    Mpart[p * 64 + ql] = m;
    Lpart[p * 64 + ql] = lsum;
  }
}

// ---------------- combine partials ----------------
template<int CHUNK>
__global__ __launch_bounds__(256) void combine_kernel(
    const float* __restrict__ Opart, const float* __restrict__ Mpart,
    const float* __restrict__ Lpart, float* __restrict__ out){
  constexpr int GS  = CHUNK / 64;
  constexpr int NG  = SEQ / CHUNK;
  constexpr int PCB = GS * NG * (NG + 1) / 2;
  const int gid = blockIdx.x * 4 + (threadIdx.x >> 6);
  const int d   = threadIdx.x & 63;
  const int b   = gid >> 12;
  const int q   = gid & (SEQ - 1);
  const int qj  = q >> 6;
  const int a   = qj / GS;
  const int nch = a + 1;
  const int p0  = b * PCB + GS * a * (a + 1) / 2 + (qj - a * GS) * (a + 1);
  const int ql  = q & 63;

  float M = -1e30f;
  for (int cc = 0; cc < nch; ++cc) M = fmaxf(M, Mpart[(p0 + cc) * 64 + ql]);
  float L = 0.f, O = 0.f;
  for (int cc = 0; cc < nch; ++cc){
    const float s = exp2f(Mpart[(p0 + cc) * 64 + ql] - M);
    L += s * Lpart[(p0 + cc) * 64 + ql];
    O += s * Opart[((size_t)(p0 + cc) * 64 + ql) * 64 + d];
  }
  out[(size_t)gid * 64 + d] = O / L;
}

extern "C" void kernel_launch(void* const* d_in, const int* in_sizes, int n_in,
                              void* d_out, int out_size, void* d_ws, size_t ws_size,
                              hipStream_t stream){
  const float* x  = (const float*)d_in[0];
  const float* Wq = (const float*)d_in[1];
  const float* Wk = (const float*)d_in[2];
  const float* Wv = (const float*)d_in[3];

  const size_t nqkv = (size_t)BATCH * SEQ * HS;
  unsigned short* Qb = (unsigned short*)d_ws;
  unsigned short* Kb = Qb + nqkv;
  unsigned short* Vt = Kb + nqkv;                     // [HS][BATCH*SEQ]
  unsigned short* Wpack = Vt + nqkv;                  // 196608 ushorts = 384 KB
  float* scratch = (float*)(Wpack + (size_t)16 * 4 * 12 * 64 * 4);

  pack_kernel<<<192, 256, 0, stream>>>(Wq, Wk, Wv, Wpack);
  proj_mfma<<<(BATCH * SEQ) / 32, 512, 0, stream>>>(x, Wpack, Qb, Kb, Vt);

  constexpr int PCB1 = (1024/64) * (SEQ/1024) * ((SEQ/1024) + 1) / 2;   // 160
  constexpr int PCB4 = (4096/64) * (SEQ/4096) * ((SEQ/4096) + 1) / 2;   // 64
  const size_t base_bytes = (3 * nqkv + (size_t)196608) * sizeof(unsigned short);
  const size_t part1 = (size_t)BATCH * PCB1 * 64 * (64 + 2) * sizeof(float);

  if (ws_size >= base_bytes + part1){
    float* Opart = scratch;
    float* Mpart = Opart + (size_t)BATCH * PCB1 * 64 * 64;
    float* Lpart = Mpart + (size_t)BATCH * PCB1 * 64;
    attn_partial<1024><<<BATCH * PCB1, 256, 0, stream>>>(Qb, Kb, Vt, Opart, Mpart, Lpart);
    combine_kernel<1024><<<BATCH * SEQ / 4, 256, 0, stream>>>(Opart, Mpart, Lpart, (float*)d_out);
  } else {
    float* Opart = scratch;
    float* Mpart = Opart + (size_t)BATCH * PCB4 * 64 * 64;
    float* Lpart = Mpart + (size_t)BATCH * PCB4 * 64;
    attn_partial<4096><<<BATCH * PCB4, 256, 0, stream>>>(Qb, Kb, Vt, Opart, Mpart, Lpart);
    combine_kernel<4096><<<BATCH * SEQ / 4, 256, 0, stream>>>(Opart, Mpart, Lpart, (float*)d_out);
  }
}

// Round 6
// 82.280 us; speedup vs baseline: 1.3286x; 1.0898x over previous
//
#include <hip/hip_runtime.h>
#include <hip/hip_bf16.h>

#define BATCH 4
#define SEQ   4096
#define EMB   1024
#define HS    64

typedef __attribute__((ext_vector_type(4)))  short  short4v;
typedef __attribute__((ext_vector_type(8)))  short  short8v;
typedef __attribute__((ext_vector_type(4)))  float  float4v;
typedef __attribute__((ext_vector_type(16))) float  float16v;
typedef __attribute__((ext_vector_type(8)))  unsigned short ushort8v;

// Q pre-scale: 1/sqrt(64) * log2(e) so softmax can use exp2 directly.
#define QSCALE 0.1803368801111204f

static __device__ __forceinline__ unsigned short f2bf(float f){
  __hip_bfloat16 h = __float2bfloat16(f);
  return *reinterpret_cast<unsigned short*>(&h);
}

// 16x16x16 bf16 (K=16), classic layout (verified in-session rounds 1-5):
//  A: lane l holds A[l%16][4*(l/16)+j]; B: B[4*(l/16)+j][l%16]; C/D: D[4*(l/16)+reg][l%16]
static __device__ __forceinline__ float4v mfma16(short4v a, short4v b, float4v c){
#if __has_builtin(__builtin_amdgcn_mfma_f32_16x16x16bf16_1k)
  return __builtin_amdgcn_mfma_f32_16x16x16bf16_1k(a, b, c, 0, 0, 0);
#else
  float4v d;
  asm("v_mfma_f32_16x16x16_bf16 %0, %1, %2, %3" : "=v"(d) : "v"(a), "v"(b), "v"(c));
  return d;
#endif
}

// 32x32x16 bf16 (gfx950 full-rate). C/D verified (m74/m101):
//   col = lane&31, row = (reg&3) + 8*(reg>>2) + 4*(lane>>5).
// A/B k-mapping assumed k = 8*(lane>>5)+j on BOTH operands (symmetric pack ->
// any true intra-instruction k-permutation cancels in the contraction).
static __device__ __forceinline__ float16v mfma32(short8v a, short8v b, float16v c){
#if __has_builtin(__builtin_amdgcn_mfma_f32_32x32x16_bf16)
  return __builtin_amdgcn_mfma_f32_32x32x16_bf16(a, b, c, 0, 0, 0);
#else
  asm("v_mfma_f32_32x32x16_bf16 %0, %1, %2, %0" : "+v"(c) : "v"(a), "v"(b));
  return c;
#endif
}

// ---------------- W pack for 32x32 frags ----------------
// Wpack32[kstep 0..63][tile 0..5][lane 0..63][j 0..7] bf16 (384 KB total)
//   holds B[k][n]: k = kstep*16 + (lane>>5)*8 + j, n = tile*32 + (lane&31)
//   tiles 0,1 -> Q (scaled by QSCALE), 2,3 -> K, 4,5 -> V
__global__ __launch_bounds__(256) void pack32_kernel(
    const float* __restrict__ Wq, const float* __restrict__ Wk, const float* __restrict__ Wv,
    unsigned short* __restrict__ Wpack){
  const int flat = blockIdx.x * 256 + threadIdx.x;   // 0..24575
  const int lane = flat & 63;
  const int f    = flat >> 6;                        // kstep*6 + tile
  const int tile = f % 6;
  const int kstep= f / 6;
  const int k0   = kstep * 16 + (lane >> 5) * 8;
  const int mat  = tile >> 1;
  const int col  = (tile & 1) * 32 + (lane & 31);
  const float* W = (mat == 0) ? Wq : (mat == 1) ? Wk : Wv;
  const float scale = (mat == 0) ? QSCALE : 1.0f;
  short8v pk;
  #pragma unroll
  for (int j = 0; j < 8; ++j) pk[j] = (short)f2bf(W[(size_t)(k0 + j) * HS + col] * scale);
  *reinterpret_cast<short8v*>(Wpack + (size_t)flat * 8) = pk;
}

// ---------------- projection GEMM: K-split, 32x32 MFMA ----------------
// Block: 512 thr = 8 waves = (kq 0..3 K-quarters) x (cg 0..1 col-halves of 96).
// Block owns 32 rows x 192 cols; fp32 partials reduced through LDS.
// Grid: 512 blocks (2/CU) -> 16 waves/CU = 4/SIMD; VGPR capped at 128.
#define LP 198   // padded LDS row stride (floats); 198%32=6 -> max 2-way bank aliasing
__global__ __launch_bounds__(512, 4) void proj_mfma(
    const float* __restrict__ x, const unsigned short* __restrict__ Wpack,
    unsigned short* __restrict__ Qb, unsigned short* __restrict__ Kb,
    unsigned short* __restrict__ Vt){
  __shared__ float Red[32 * LP];                  // 25.3 KB
  const int tid  = threadIdx.x;
  const int lane = tid & 63;
  const int w    = tid >> 6;                      // 0..7
  const int kq   = w >> 1;                        // K-quarter 0..3
  const int cg   = w & 1;                         // col half: tiles cg*3 .. cg*3+2
  const int grow0 = blockIdx.x * 32;

  float16v acc0 = {0,0,0,0,0,0,0,0,0,0,0,0,0,0,0,0};
  float16v acc1 = {0,0,0,0,0,0,0,0,0,0,0,0,0,0,0,0};
  float16v acc2 = {0,0,0,0,0,0,0,0,0,0,0,0,0,0,0,0};

  // A: lane covers row = grow0 + (lane&31), k = kq*256 + t*16 + (lane>>5)*8 + j
  const float* xr = x + (size_t)(grow0 + (lane & 31)) * EMB + kq * 256 + ((lane >> 5) << 3);
  const unsigned short* wp = Wpack + lane * 8;
  const int fbase = (kq * 16) * 6 + cg * 3;       // fragment index of (t=0, tile cg*3)

  // preload t=0
  float4 xa0 = *reinterpret_cast<const float4*>(xr);
  float4 xa1 = *reinterpret_cast<const float4*>(xr + 4);
  short8v b0 = *reinterpret_cast<const short8v*>(wp + (size_t)(fbase    ) * 512);
  short8v b1 = *reinterpret_cast<const short8v*>(wp + (size_t)(fbase + 1) * 512);
  short8v b2 = *reinterpret_cast<const short8v*>(wp + (size_t)(fbase + 2) * 512);

  #pragma unroll
  for (int t = 0; t < 16; ++t){
    short8v af;
    af[0] = (short)f2bf(xa0.x); af[1] = (short)f2bf(xa0.y);
    af[2] = (short)f2bf(xa0.z); af[3] = (short)f2bf(xa0.w);
    af[4] = (short)f2bf(xa1.x); af[5] = (short)f2bf(xa1.y);
    af[6] = (short)f2bf(xa1.z); af[7] = (short)f2bf(xa1.w);
    float4 nx0, nx1; short8v nb0, nb1, nb2;
    if (t < 15){
      nx0 = *reinterpret_cast<const float4*>(xr + (t + 1) * 16);
      nx1 = *reinterpret_cast<const float4*>(xr + (t + 1) * 16 + 4);
      const unsigned short* wk = wp + (size_t)(fbase + (t + 1) * 6) * 512;
      nb0 = *reinterpret_cast<const short8v*>(wk);
      nb1 = *reinterpret_cast<const short8v*>(wk + 512);
      nb2 = *reinterpret_cast<const short8v*>(wk + 1024);
    }
    acc0 = mfma32(af, b0, acc0);
    acc1 = mfma32(af, b1, acc1);
    acc2 = mfma32(af, b2, acc2);
    if (t < 15){ xa0 = nx0; xa1 = nx1; b0 = nb0; b1 = nb1; b2 = nb2; }
  }

  // ---- LDS reduction over the 4 K-quarters ----
  // lane's C: tile tt -> global col cg*96 + tt*32 + (lane&31); row = (reg&3)+8*(reg>>2)+4*(lane>>5)
  const int colb = cg * 96 + (lane & 31);
  const int rsh  = 4 * (lane >> 5);
  #define RED_OP(op) { \
    _Pragma("unroll") \
    for (int reg = 0; reg < 16; ++reg){ \
      const int row = (reg & 3) + 8 * (reg >> 2) + rsh; \
      Red[row * LP + colb     ] op acc0[reg]; \
      Red[row * LP + colb + 32] op acc1[reg]; \
      Red[row * LP + colb + 64] op acc2[reg]; \
    }}
  if (kq == 0) RED_OP(=)
  __syncthreads();
  if (kq == 1) RED_OP(+=)
  __syncthreads();
  if (kq == 2) RED_OP(+=)
  __syncthreads();
  if (kq == 3) RED_OP(+=)
  __syncthreads();
  #undef RED_OP

  // ---- epilogue: cols 0..63 -> Q, 64..127 -> K (row-major), 128..191 -> V (transposed) ----
  {
    const int row = tid >> 4;                     // 0..31
    const int c16 = tid & 15;                     // 0..15
    ushort8v pk;
    #pragma unroll
    for (int i = 0; i < 8; ++i) pk[i] = f2bf(Red[row * LP + c16 * 8 + i]);
    unsigned short* dst = (c16 < 8) ? (Qb + (size_t)(grow0 + row) * HS + c16 * 8)
                                    : (Kb + (size_t)(grow0 + row) * HS + (c16 - 8) * 8);
    *reinterpret_cast<ushort8v*>(dst) = pk;
  }
  {
    const int vcol = tid >> 3;                    // 0..63
    const int rg   = tid & 7;                     // 0..7
    short4v pk;
    #pragma unroll
    for (int j = 0; j < 4; ++j) pk[j] = (short)f2bf(Red[(rg * 4 + j) * LP + 128 + vcol]);
    *reinterpret_cast<short4v*>(Vt + (size_t)vcol * (BATCH * SEQ) + grow0 + rg * 4) = pk;
  }
}

// ---------------- flash attention partials, causal, kv-split ----------------
template<int CHUNK>
__global__ __launch_bounds__(256) void attn_partial(
    const unsigned short* __restrict__ Qb, const unsigned short* __restrict__ Kb,
    const unsigned short* __restrict__ Vt,
    float* __restrict__ Opart, float* __restrict__ Mpart, float* __restrict__ Lpart){
  constexpr int GS  = CHUNK / 64;
  constexpr int NG  = SEQ / CHUNK;
  constexpr int PCB = GS * NG * (NG + 1) / 2;
  constexpr int LDP = 72;

  __shared__ unsigned short Ks[64 * LDP];
  __shared__ unsigned short Vs[64 * LDP];

  const int b = blockIdx.x / PCB;
  const int g = blockIdx.x % PCB;
  int a = 0, accb = 0;
  while (g >= accb + GS * (a + 1)) { accb += GS * (a + 1); ++a; }
  const int rem = g - accb;
  const int qj  = a * GS + rem / (a + 1);
  const int c   = rem % (a + 1);

  const int tid  = threadIdx.x;
  const int lane = tid & 63;
  const int w    = tid >> 6;
  const int ln   = lane & 15;
  const int lg   = lane >> 4;

  const size_t bbase = (size_t)b * SEQ * HS;
  const int qbase  = qj * 64 + w * 16;
  const int cstart = c * CHUNK;
  const int kend   = min(cstart + CHUNK, qj * 64 + 64);
  const int nt     = (kend - cstart) >> 6;

  short4v qf[4];
  #pragma unroll
  for (int ds = 0; ds < 4; ++ds)
    qf[ds] = *reinterpret_cast<const short4v*>(Qb + bbase + (size_t)(qbase + ln) * HS + ds * 16 + lg * 4);

  float m = -1e30f, lsum = 0.f;
  float4v oacc[4];
  #pragma unroll
  for (int dt = 0; dt < 4; ++dt) oacc[dt] = (float4v){0.f, 0.f, 0.f, 0.f};

  const int srow = tid >> 2;
  const int sseg = tid & 3;
  const unsigned short* Kg = Kb + bbase + (size_t)(cstart + srow) * HS + sseg * 16;
  const unsigned short* Vg = Vt + (size_t)srow * (BATCH * SEQ) + b * SEQ + cstart + sseg * 16;
  ushort8v kr0, kr1, vr0, vr1;
  kr0 = reinterpret_cast<const ushort8v*>(Kg)[0];
  kr1 = reinterpret_cast<const ushort8v*>(Kg)[1];
  vr0 = reinterpret_cast<const ushort8v*>(Vg)[0];
  vr1 = reinterpret_cast<const ushort8v*>(Vg)[1];

  for (int t = 0; t < nt; ++t){
    *reinterpret_cast<ushort8v*>(&Ks[srow * LDP + sseg * 16])     = kr0;
    *reinterpret_cast<ushort8v*>(&Ks[srow * LDP + sseg * 16 + 8]) = kr1;
    *reinterpret_cast<ushort8v*>(&Vs[srow * LDP + sseg * 16])     = vr0;
    *reinterpret_cast<ushort8v*>(&Vs[srow * LDP + sseg * 16 + 8]) = vr1;
    __syncthreads();
    if (t + 1 < nt){
      const unsigned short* Kn = Kg + (size_t)(t + 1) * 64 * HS;
      const unsigned short* Vn = Vg + (t + 1) * 64;
      kr0 = reinterpret_cast<const ushort8v*>(Kn)[0];
      kr1 = reinterpret_cast<const ushort8v*>(Kn)[1];
      vr0 = reinterpret_cast<const ushort8v*>(Vn)[0];
      vr1 = reinterpret_cast<const ushort8v*>(Vn)[1];
    }

    const int k0 = cstart + t * 64;
    if (k0 <= qbase + 15){
      float4v st[4];
      #pragma unroll
      for (int kt = 0; kt < 4; ++kt){
        float4v accv = (float4v){0.f, 0.f, 0.f, 0.f};
        #pragma unroll
        for (int ds = 0; ds < 4; ++ds){
          short4v av = *reinterpret_cast<const short4v*>(&Ks[(kt * 16 + ln) * LDP + ds * 16 + lg * 4]);
          accv = mfma16(av, qf[ds], accv);
        }
        st[kt] = accv;
      }
      const int gq = qbase + ln;
      #pragma unroll
      for (int kt = 0; kt < 4; ++kt){
        if (k0 + kt * 16 + 15 > qbase){
          #pragma unroll
          for (int r = 0; r < 4; ++r){
            const int gk = k0 + kt * 16 + lg * 4 + r;
            if (gk > gq) st[kt][r] = -1e30f;
          }
        }
      }
      float tmax = -1e30f;
      #pragma unroll
      for (int kt = 0; kt < 4; ++kt)
        #pragma unroll
        for (int r = 0; r < 4; ++r) tmax = fmaxf(tmax, st[kt][r]);
      tmax = fmaxf(tmax, __shfl_xor(tmax, 16, 64));
      tmax = fmaxf(tmax, __shfl_xor(tmax, 32, 64));
      const float mnew = fmaxf(m, tmax);
      const float corr = exp2f(m - mnew);
      float psum = 0.f;
      short4v pb[4];
      #pragma unroll
      for (int kt = 0; kt < 4; ++kt){
        #pragma unroll
        for (int r = 0; r < 4; ++r){
          const float p = exp2f(st[kt][r] - mnew);
          psum += p;
          pb[kt][r] = (short)f2bf(p);
        }
      }
      psum += __shfl_xor(psum, 16, 64);
      psum += __shfl_xor(psum, 32, 64);
      lsum = lsum * corr + psum;
      m = mnew;
      #pragma unroll
      for (int dt = 0; dt < 4; ++dt){
        oacc[dt][0] *= corr; oacc[dt][1] *= corr; oacc[dt][2] *= corr; oacc[dt][3] *= corr;
      }
      #pragma unroll
      for (int dt = 0; dt < 4; ++dt){
        #pragma unroll
        for (int kt = 0; kt < 4; ++kt){
          short4v av = *reinterpret_cast<const short4v*>(&Vs[(dt * 16 + ln) * LDP + kt * 16 + lg * 4]);
          oacc[dt] = mfma16(av, pb[kt], oacc[dt]);
        }
      }
    }
    __syncthreads();
  }

  const int p = b * PCB + g;
  const int ql = w * 16 + ln;
  float* Op = Opart + ((size_t)p * 64 + ql) * 64;
  #pragma unroll
  for (int dt = 0; dt < 4; ++dt)
    *reinterpret_cast<float4v*>(Op + dt * 16 + lg * 4) = oacc[dt];
  if (lg == 0){
    Mpart[p * 64 + ql] = m;
    Lpart[p * 64 + ql] = lsum;
  }
}

// ---------------- combine partials ----------------
template<int CHUNK>
__global__ __launch_bounds__(256) void combine_kernel(
    const float* __restrict__ Opart, const float* __restrict__ Mpart,
    const float* __restrict__ Lpart, float* __restrict__ out){
  constexpr int GS  = CHUNK / 64;
  constexpr int NG  = SEQ / CHUNK;
  constexpr int PCB = GS * NG * (NG + 1) / 2;
  const int gid = blockIdx.x * 4 + (threadIdx.x >> 6);
  const int d   = threadIdx.x & 63;
  const int b   = gid >> 12;
  const int q   = gid & (SEQ - 1);
  const int qj  = q >> 6;
  const int a   = qj / GS;
  const int nch = a + 1;
  const int p0  = b * PCB + GS * a * (a + 1) / 2 + (qj - a * GS) * (a + 1);
  const int ql  = q & 63;

  float M = -1e30f;
  for (int cc = 0; cc < nch; ++cc) M = fmaxf(M, Mpart[(p0 + cc) * 64 + ql]);
  float L = 0.f, O = 0.f;
  for (int cc = 0; cc < nch; ++cc){
    const float s = exp2f(Mpart[(p0 + cc) * 64 + ql] - M);
    L += s * Lpart[(p0 + cc) * 64 + ql];
    O += s * Opart[((size_t)(p0 + cc) * 64 + ql) * 64 + d];
  }
  out[(size_t)gid * 64 + d] = O / L;
}

extern "C" void kernel_launch(void* const* d_in, const int* in_sizes, int n_in,
                              void* d_out, int out_size, void* d_ws, size_t ws_size,
                              hipStream_t stream){
  const float* x  = (const float*)d_in[0];
  const float* Wq = (const float*)d_in[1];
  const float* Wk = (const float*)d_in[2];
  const float* Wv = (const float*)d_in[3];

  const size_t nqkv = (size_t)BATCH * SEQ * HS;
  unsigned short* Qb = (unsigned short*)d_ws;
  unsigned short* Kb = Qb + nqkv;
  unsigned short* Vt = Kb + nqkv;                     // [HS][BATCH*SEQ]
  unsigned short* Wpack = Vt + nqkv;                  // 196608 ushorts = 384 KB
  float* scratch = (float*)(Wpack + (size_t)196608);

  pack32_kernel<<<96, 256, 0, stream>>>(Wq, Wk, Wv, Wpack);
  proj_mfma<<<(BATCH * SEQ) / 32, 512, 0, stream>>>(x, Wpack, Qb, Kb, Vt);

  constexpr int PCB1 = (1024/64) * (SEQ/1024) * ((SEQ/1024) + 1) / 2;   // 160
  constexpr int PCB4 = (4096/64) * (SEQ/4096) * ((SEQ/4096) + 1) / 2;   // 64
  const size_t base_bytes = (3 * nqkv + (size_t)196608) * sizeof(unsigned short);
  const size_t part1 = (size_t)BATCH * PCB1 * 64 * (64 + 2) * sizeof(float);

  if (ws_size >= base_bytes + part1){
    float* Opart = scratch;
    float* Mpart = Opart + (size_t)BATCH * PCB1 * 64 * 64;
    float* Lpart = Mpart + (size_t)BATCH * PCB1 * 64;
    attn_partial<1024><<<BATCH * PCB1, 256, 0, stream>>>(Qb, Kb, Vt, Opart, Mpart, Lpart);
    combine_kernel<1024><<<BATCH * SEQ / 4, 256, 0, stream>>>(Opart, Mpart, Lpart, (float*)d_out);
  } else {
    float* Opart = scratch;
    float* Mpart = Opart + (size_t)BATCH * PCB4 * 64 * 64;
    float* Lpart = Mpart + (size_t)BATCH * PCB4 * 64;
    attn_partial<4096><<<BATCH * PCB4, 256, 0, stream>>>(Qb, Kb, Vt, Opart, Mpart, Lpart);
    combine_kernel<4096><<<BATCH * SEQ / 4, 256, 0, stream>>>(Opart, Mpart, Lpart, (float*)d_out);
  }
}